// Round 1
// baseline (2551.958 us; speedup 1.0000x reference)
//
#include <hip/hip_runtime.h>
#include <hip/hip_bf16.h>
#include <math.h>

// ---------------- problem dims (compile-time) ----------------
constexpr int B = 32, T = 80, D = 128, H = 8, DH = 64, DMLP = 512, L = 8, V = 50257;
constexpr int M = B * T;            // 2560 token rows
constexpr int HD = H * DH;          // 512
constexpr int QKVN = 3 * HD;        // 1536

__device__ __forceinline__ float gelu_f(float x) {
    // exact gelu (approximate=False): 0.5*x*(1+erf(x/sqrt(2)))
    return 0.5f * x * (1.0f + erff(x * 0.70710678118654752f));
}

// ---------------- embedding: h = tok_emb[x] + pos_emb ----------------
__global__ __launch_bounds__(256)
void embed_kernel(const int* __restrict__ x, const float* __restrict__ tok,
                  const float* __restrict__ pos, float* __restrict__ h) {
    int row = blockIdx.x * 2 + (threadIdx.x >> 7);   // 2 rows / block
    int d   = threadIdx.x & 127;
    int t   = row % T;
    h[(size_t)row * D + d] = tok[(size_t)x[row] * D + d] + pos[t * D + d];
}

// ---------------- layernorm (two-pass, biased var, eps=1e-5) ----------------
__global__ __launch_bounds__(256)
void ln_kernel(const float* __restrict__ in, const float* __restrict__ g,
               const float* __restrict__ b, float* __restrict__ out) {
    int wid = threadIdx.x >> 6, lane = threadIdx.x & 63;
    int row = blockIdx.x * 4 + wid;                  // one wave per row
    const float* r = in + (size_t)row * D;
    float x0 = r[lane], x1 = r[64 + lane];
    float s = x0 + x1;
    #pragma unroll
    for (int off = 32; off; off >>= 1) s += __shfl_xor(s, off);
    float mean = s * (1.0f / 128.0f);
    float d0 = x0 - mean, d1 = x1 - mean;
    float q = d0 * d0 + d1 * d1;
    #pragma unroll
    for (int off = 32; off; off >>= 1) q += __shfl_xor(q, off);
    float inv = rsqrtf(q * (1.0f / 128.0f) + 1e-5f);
    out[(size_t)row * D + lane]      = d0 * inv * g[lane]      + b[lane];
    out[(size_t)row * D + 64 + lane] = d1 * inv * g[64 + lane] + b[64 + lane];
}

// ---------------- repack Wq/Wk/Wv [L,H,D,DH] -> [L, D, 3*H*DH] ----------------
__global__ __launch_bounds__(256)
void repack_qkv(const float* __restrict__ Wq, const float* __restrict__ Wk,
                const float* __restrict__ Wv, float* __restrict__ Wr) {
    int idx = blockIdx.x * 256 + threadIdx.x;        // < L*D*1536
    int c    = idx % QKVN;
    int rest = idx / QKVN;                           // l*D + d
    int d    = rest & 127;
    int l    = rest >> 7;
    int e  = c & 63;
    int hh = (c >> 6) & 7;
    int w  = c >> 9;                                 // 0=q,1=k,2=v
    const float* src = (w == 0) ? Wq : (w == 1) ? Wk : Wv;
    Wr[idx] = src[(((size_t)l * H + hh) * D + d) * DH + e];
}

// ---------------- generic GEMM, K-chunk = 128 staged in LDS ----------------
// A[., lda] (chunk z uses cols z*128..), W[K, ldw] row-major (chunk z uses rows z*128..),
// out: if SPLIT, partial planes pbuf[z][M][N]; else Cout[., ldc] with bias/act.
template<int CT, bool SPLIT>
__global__ __launch_bounds__(256)
void gemm128(const float* __restrict__ A, int lda,
             const float* __restrict__ W, int ldw, int N,
             const float* __restrict__ bias,
             float* __restrict__ Cout, int ldc, int act) {
    constexpr int BM = 32, RT = 8;
    __shared__ float aS[BM][128];
    const int tid = threadIdx.x;
    const int tx = tid & 63, ty = tid >> 6;
    const int row0 = blockIdx.y * BM;
    const int c0 = blockIdx.x * (64 * CT);
    const float* Ak = A + (size_t)blockIdx.z * 128;
    const float* Wk = W + (size_t)blockIdx.z * 128 * ldw;

    // stage A tile: 32 rows x 128 floats (1024 float4, 4 per thread)
    for (int i = tid; i < BM * 32; i += 256) {
        int r = i >> 5, q = i & 31;
        *reinterpret_cast<float4*>(&aS[r][q * 4]) =
            *reinterpret_cast<const float4*>(Ak + (size_t)(row0 + r) * lda + q * 4);
    }
    __syncthreads();

    float acc[RT][CT];
    #pragma unroll
    for (int r = 0; r < RT; r++)
        #pragma unroll
        for (int j = 0; j < CT; j++) acc[r][j] = 0.0f;

    int col[CT]; bool cok[CT];
    #pragma unroll
    for (int j = 0; j < CT; j++) { col[j] = c0 + tx + j * 64; cok[j] = col[j] < N; }

    #pragma unroll 4
    for (int k4 = 0; k4 < 32; k4++) {
        float w[4][CT];
        #pragma unroll
        for (int kk = 0; kk < 4; kk++)
            #pragma unroll
            for (int j = 0; j < CT; j++)
                w[kk][j] = cok[j] ? Wk[(size_t)(k4 * 4 + kk) * ldw + col[j]] : 0.0f;
        #pragma unroll
        for (int r = 0; r < RT; r++) {
            float4 av = *reinterpret_cast<const float4*>(&aS[ty * RT + r][k4 * 4]);
            #pragma unroll
            for (int j = 0; j < CT; j++)
                acc[r][j] = fmaf(av.w, w[3][j],
                            fmaf(av.z, w[2][j],
                            fmaf(av.y, w[1][j],
                            fmaf(av.x, w[0][j], acc[r][j]))));
        }
    }

    if (SPLIT) {
        float* outp = Cout + (size_t)blockIdx.z * M * N;
        #pragma unroll
        for (int r = 0; r < RT; r++) {
            int row = row0 + ty * RT + r;
            #pragma unroll
            for (int j = 0; j < CT; j++)
                if (cok[j]) outp[(size_t)row * N + col[j]] = acc[r][j];
        }
    } else {
        #pragma unroll
        for (int r = 0; r < RT; r++) {
            int row = row0 + ty * RT + r;
            #pragma unroll
            for (int j = 0; j < CT; j++) if (cok[j]) {
                float v = acc[r][j];
                if (bias) v += bias[col[j]];
                if (act)  v = gelu_f(v);
                Cout[(size_t)row * ldc + col[j]] = v;
            }
        }
    }
}

// ---------------- combine split-K partials + bias, residual into h ----------------
__global__ __launch_bounds__(256)
void combine4(const float* __restrict__ p, const float* __restrict__ bias,
              float* __restrict__ out) {
    int i = blockIdx.x * 256 + threadIdx.x;          // < M*128
    constexpr int plane = M * D;
    float v = p[i] + p[i + plane] + p[i + 2 * plane] + p[i + 3 * plane] + bias[i & 127];
    out[i] += v;
}

// ---------------- attention: scores + causal softmax -> p ----------------
__global__ __launch_bounds__(256)
void attn_scores(const float* __restrict__ qkv, float* __restrict__ p) {
    __shared__ float qS[T][DH];      // 20 KB
    __shared__ float pS[T][T];       // 25.6 KB
    int bh = blockIdx.x;
    int b = bh >> 3, h = bh & 7;
    const float* base = qkv + (size_t)b * T * QKVN + h * DH;

    for (int i = threadIdx.x; i < T * (DH / 4); i += 256) {  // q tile, float4
        int t = i >> 4, q4 = i & 15;
        *reinterpret_cast<float4*>(&qS[t][q4 * 4]) =
            *reinterpret_cast<const float4*>(base + (size_t)t * QKVN + q4 * 4);
    }
    __syncthreads();

    const float* kbase = base + HD;  // k lives at +512
    const float scale = 0.125f;      // 1/sqrt(64)
    for (int i = threadIdx.x; i < T * T; i += 256) {
        int t = i / T, s = i % T;
        float val = -INFINITY;
        if (s <= t) {
            const float* krow = kbase + (size_t)s * QKVN;
            float acc = 0.0f;
            #pragma unroll
            for (int e4 = 0; e4 < DH / 4; e4++) {
                float4 kv = *reinterpret_cast<const float4*>(krow + e4 * 4);
                float4 qv = *reinterpret_cast<const float4*>(&qS[t][e4 * 4]);
                acc += qv.x * kv.x + qv.y * kv.y + qv.z * kv.z + qv.w * kv.w;
            }
            val = acc * scale;
        }
        pS[t][s] = val;
    }
    __syncthreads();

    int wid = threadIdx.x >> 6, lane = threadIdx.x & 63;
    for (int t = wid; t < T; t += 4) {               // one wave per row
        float v0 = pS[t][lane];
        float v1 = (lane < T - 64) ? pS[t][64 + lane] : -INFINITY;
        float mx = fmaxf(v0, v1);
        #pragma unroll
        for (int off = 32; off; off >>= 1) mx = fmaxf(mx, __shfl_xor(mx, off));
        float e0 = expf(v0 - mx);                    // exp(-inf)=0 handles mask
        float e1 = (lane < T - 64) ? expf(v1 - mx) : 0.0f;
        float ss = e0 + e1;
        #pragma unroll
        for (int off = 32; off; off >>= 1) ss += __shfl_xor(ss, off);
        float rs = 1.0f / ss;
        pS[t][lane] = e0 * rs;
        if (lane < T - 64) pS[t][64 + lane] = e1 * rs;
    }
    __syncthreads();

    float* pf = &pS[0][0];
    float* pg = p + (size_t)bh * T * T;
    for (int i = threadIdx.x; i < (T * T) / 4; i += 256)
        reinterpret_cast<float4*>(pg)[i] = reinterpret_cast<const float4*>(pf)[i];
}

// ---------------- attention: o = p @ v, write [B,T,H*DH] ----------------
__global__ __launch_bounds__(256)
void attn_pv(const float* __restrict__ qkv, const float* __restrict__ p,
             float* __restrict__ o) {
    __shared__ float vS[T][DH];      // 20 KB
    __shared__ float pS[T][T];       // 25.6 KB
    int bh = blockIdx.x;
    int b = bh >> 3, h = bh & 7;
    const float* vbase = qkv + (size_t)b * T * QKVN + h * DH + 2 * HD;

    for (int i = threadIdx.x; i < T * (DH / 4); i += 256) {
        int t = i >> 4, q4 = i & 15;
        *reinterpret_cast<float4*>(&vS[t][q4 * 4]) =
            *reinterpret_cast<const float4*>(vbase + (size_t)t * QKVN + q4 * 4);
    }
    const float* pg = p + (size_t)bh * T * T;
    float* pf = &pS[0][0];
    for (int i = threadIdx.x; i < (T * T) / 4; i += 256)
        reinterpret_cast<float4*>(pf)[i] = reinterpret_cast<const float4*>(pg)[i];
    __syncthreads();

    for (int i = threadIdx.x; i < T * DH; i += 256) {
        int t = i >> 6, e = i & 63;                  // wave: same t, e=0..63
        float acc = 0.0f;
        for (int s = 0; s <= t; s++) acc += pS[t][s] * vS[s][e];
        o[((size_t)b * T + t) * HD + h * DH + e] = acc;
    }
}

// ---------------- launch ----------------
extern "C" void kernel_launch(void* const* d_in, const int* in_sizes, int n_in,
                              void* d_out, int out_size, void* d_ws, size_t ws_size,
                              hipStream_t stream) {
    const int*   x     = (const int*)d_in[0];
    const float* tok   = (const float*)d_in[1];
    const float* pos   = (const float*)d_in[2];
    const float* Wq    = (const float*)d_in[3];
    const float* Wk    = (const float*)d_in[4];
    const float* Wv    = (const float*)d_in[5];
    const float* Wo    = (const float*)d_in[6];
    const float* bo    = (const float*)d_in[7];
    const float* ln1g  = (const float*)d_in[8];
    const float* ln1b  = (const float*)d_in[9];
    const float* ln2g  = (const float*)d_in[10];
    const float* ln2b  = (const float*)d_in[11];
    const float* W1    = (const float*)d_in[12];
    const float* b1    = (const float*)d_in[13];
    const float* W2    = (const float*)d_in[14];
    const float* b2    = (const float*)d_in[15];
    const float* lnfg  = (const float*)d_in[16];
    const float* lnfb  = (const float*)d_in[17];
    const float* Wcls  = (const float*)d_in[18];
    const float* bcls  = (const float*)d_in[19];
    float* out = (float*)d_out;

    float* ws   = (float*)d_ws;
    float* h    = ws;                       // M*D
    float* a    = h    + (size_t)M * D;     // M*D
    float* qkv  = a    + (size_t)M * D;     // M*1536
    float* o    = qkv  + (size_t)M * QKVN;  // M*512
    float* mlp  = o    + (size_t)M * HD;    // M*512
    float* p    = mlp  + (size_t)M * DMLP;  // B*H*T*T
    float* Wr   = p    + (size_t)B * H * T * T;   // L*D*1536
    float* pbuf = Wr   + (size_t)L * D * QKVN;    // 4*M*128

    repack_qkv<<<(L * D * QKVN) / 256, 256, 0, stream>>>(Wq, Wk, Wv, Wr);
    embed_kernel<<<M / 2, 256, 0, stream>>>(x, tok, pos, h);

    for (int l = 0; l < L; l++) {
        ln_kernel<<<M / 4, 256, 0, stream>>>(h, ln1g + l * D, ln1b + l * D, a);
        // qkv = a @ Wr[l]  : [2560,128]@[128,1536]
        gemm128<4, false><<<dim3(QKVN / 256, M / 32, 1), 256, 0, stream>>>(
            a, D, Wr + (size_t)l * D * QKVN, QKVN, QKVN, nullptr, qkv, QKVN, 0);
        attn_scores<<<B * H, 256, 0, stream>>>(qkv, p);
        attn_pv<<<B * H, 256, 0, stream>>>(qkv, p, o);
        // h += o @ Wo[l] + bo[l] : [2560,512]@[512,128], split-K=4
        gemm128<2, true><<<dim3(1, M / 32, 4), 256, 0, stream>>>(
            o, HD, Wo + (size_t)l * HD * D, D, D, nullptr, pbuf, D, 0);
        combine4<<<(M * D) / 256, 256, 0, stream>>>(pbuf, bo + l * D, h);

        ln_kernel<<<M / 4, 256, 0, stream>>>(h, ln2g + l * D, ln2b + l * D, a);
        // mlp = gelu(a @ W1[l] + b1[l]) : [2560,128]@[128,512]
        gemm128<2, false><<<dim3(DMLP / 128, M / 32, 1), 256, 0, stream>>>(
            a, D, W1 + (size_t)l * D * DMLP, DMLP, DMLP, b1 + l * DMLP, mlp, DMLP, 1);
        // h += mlp @ W2[l] + b2[l] : [2560,512]@[512,128], split-K=4
        gemm128<2, true><<<dim3(1, M / 32, 4), 256, 0, stream>>>(
            mlp, DMLP, W2 + (size_t)l * DMLP * D, D, D, nullptr, pbuf, D, 0);
        combine4<<<(M * D) / 256, 256, 0, stream>>>(pbuf, b2 + l * D, h);
    }

    ln_kernel<<<M / 4, 256, 0, stream>>>(h, lnfg, lnfb, a);
    // logits = a @ Wcls + bcls : [2560,128]@[128,50257]
    gemm128<4, false><<<dim3((V + 255) / 256, M / 32, 1), 256, 0, stream>>>(
        a, D, Wcls, V, V, bcls, out, V, 0);
}

// Round 5
// 1426.538 us; speedup vs baseline: 1.7889x; 1.7889x over previous
//
#include <hip/hip_runtime.h>
#include <hip/hip_bf16.h>
#include <hip/hip_fp16.h>
#include <math.h>

// ---------------- problem dims (compile-time) ----------------
constexpr int B = 32, T = 80, D = 128, H = 8, DH = 64, DMLP = 512, L = 8, V = 50257;
constexpr int M = B * T;            // 2560 token rows
constexpr int HD = H * DH;          // 512
constexpr int QKVN = 3 * HD;        // 1536
constexpr int VPAD = 50304;         // 393*128, padded classifier cols

typedef _Float16 f16x8 __attribute__((ext_vector_type(8)));
typedef float f32x4 __attribute__((ext_vector_type(4)));

__device__ __forceinline__ float gelu_f(float x) {
    return 0.5f * x * (1.0f + erff(x * 0.70710678118654752f));
}

// ---- embedding + first LN: h = tok_emb[x]+pos_emb; a = LN(h,g,b) fp16 -------
__global__ __launch_bounds__(256)
void embed_ln(const int* __restrict__ x, const float* __restrict__ tok,
              const float* __restrict__ pos, const float* __restrict__ g,
              const float* __restrict__ bb, float* __restrict__ h,
              __half* __restrict__ out) {
    int wid = threadIdx.x >> 6, lane = threadIdx.x & 63;
    int row = blockIdx.x * 4 + wid;
    int t = row % T;
    const float* te = tok + (size_t)x[row] * D;
    const float* pe = pos + (size_t)t * D;
    float v0 = te[lane]      + pe[lane];
    float v1 = te[64 + lane] + pe[64 + lane];
    int i0 = row * D + lane, i1 = i0 + 64;
    h[i0] = v0; h[i1] = v1;
    float s = v0 + v1;
    #pragma unroll
    for (int off = 32; off; off >>= 1) s += __shfl_xor(s, off);
    float mean = s * (1.0f / 128.0f);
    float d0 = v0 - mean, d1 = v1 - mean;
    float q = d0 * d0 + d1 * d1;
    #pragma unroll
    for (int off = 32; off; off >>= 1) q += __shfl_xor(q, off);
    float inv = rsqrtf(q * (1.0f / 128.0f) + 1e-5f);
    out[i0] = __float2half(d0 * inv * g[lane]      + bb[lane]);
    out[i1] = __float2half(d1 * inv * g[64 + lane] + bb[64 + lane]);
}

// ---- fused: h += (sum of 4 split-K planes + bias); then LN(h) -> fp16 out ----
__global__ __launch_bounds__(256)
void combine_ln(const float* __restrict__ p, const float* __restrict__ bias,
                const float* __restrict__ g, const float* __restrict__ bb,
                float* __restrict__ h, __half* __restrict__ out) {
    constexpr int plane = M * D;
    int wid = threadIdx.x >> 6, lane = threadIdx.x & 63;
    int row = blockIdx.x * 4 + wid;
    int i0 = row * D + lane, i1 = i0 + 64;
    float v0 = h[i0] + p[i0] + p[i0 + plane] + p[i0 + 2 * plane] + p[i0 + 3 * plane]
             + bias[lane];
    float v1 = h[i1] + p[i1] + p[i1 + plane] + p[i1 + 2 * plane] + p[i1 + 3 * plane]
             + bias[64 + lane];
    h[i0] = v0; h[i1] = v1;
    float s = v0 + v1;
    #pragma unroll
    for (int off = 32; off; off >>= 1) s += __shfl_xor(s, off);
    float mean = s * (1.0f / 128.0f);
    float d0 = v0 - mean, d1 = v1 - mean;
    float q = d0 * d0 + d1 * d1;
    #pragma unroll
    for (int off = 32; off; off >>= 1) q += __shfl_xor(q, off);
    float inv = rsqrtf(q * (1.0f / 128.0f) + 1e-5f);
    out[i0] = __float2half(d0 * inv * g[lane]      + bb[lane]);
    out[i1] = __float2half(d1 * inv * g[64 + lane] + bb[64 + lane]);
}

// ---------------- weight prep: fp32 -> fp16 transposed [N][K] ----------------
__global__ __launch_bounds__(256)
void prep_small(const float* __restrict__ Wq, const float* __restrict__ Wk,
                const float* __restrict__ Wv, const float* __restrict__ Wo,
                const float* __restrict__ W1, const float* __restrict__ W2,
                __half* __restrict__ WqkvT, __half* __restrict__ WoT,
                __half* __restrict__ W1T, __half* __restrict__ W2T) {
    int id = blockIdx.x * 256 + threadIdx.x;
    if (id < L * QKVN * D) {                 // 1572864
        int d = id & 127; int lc = id >> 7; int c = lc % QKVN; int l = lc / QKVN;
        int e = c & 63, hh = (c >> 6) & 7, wsel = c >> 9;
        const float* src = (wsel == 0) ? Wq : (wsel == 1) ? Wk : Wv;
        WqkvT[id] = __float2half(src[(((size_t)l * H + hh) * D + d) * DH + e]);
    } else {
        int id2 = id - L * QKVN * D;
        int which = id2 >> 19;               // /524288
        int r = id2 & 524287;
        if (which == 0) {                    // WoT[n][k] = Wo[l][k][n]
            int k = r & 511, n = (r >> 9) & 127, l = r >> 16;
            WoT[r] = __float2half(Wo[((size_t)l * 512 + k) * 128 + n]);
        } else if (which == 1) {             // W1T[n][k] = W1[l][k][n]
            int k = r & 127, n = (r >> 7) & 511, l = r >> 16;
            W1T[r] = __float2half(W1[((size_t)l * 128 + k) * 512 + n]);
        } else {                             // W2T like WoT
            int k = r & 511, n = (r >> 9) & 127, l = r >> 16;
            W2T[r] = __float2half(W2[((size_t)l * 512 + k) * 128 + n]);
        }
    }
}

// ---- Wcls [128][50257] -> WclsT [50304][128] fp16 (LDS transpose, 16.9 KB) ----
__global__ __launch_bounds__(256)
void prep_wcls(const float* __restrict__ Wcls, __half* __restrict__ WT) {
    __shared__ float tile[128][33];          // 32 n-cols per block, +1 pad
    int n0 = blockIdx.x * 32;
    for (int i = threadIdx.x; i < 128 * 32; i += 256) {
        int k = i >> 5, j = i & 31;
        int n = n0 + j;
        tile[k][j] = (n < V) ? Wcls[(size_t)k * V + n] : 0.0f;
    }
    __syncthreads();
    for (int i = threadIdx.x; i < 32 * 64; i += 256) {
        int j = i >> 6, kp = i & 63;         // kp = half2 index along k
        __half2 hv = __floats2half2_rn(tile[2 * kp][j], tile[2 * kp + 1][j]);
        *reinterpret_cast<__half2*>(WT + (size_t)(n0 + j) * 128 + 2 * kp) = hv;
    }
}

// ---------------- generic fp16 MFMA GEMM, K-chunk=128 (4 k-steps of 32) -------
// A [M][lda] fp16 row-major (k offset z*128), BT [N][ldb] fp16 (k-contiguous).
// MODE 1: fp32 partial plane z -> outF[z][M][128]
// MODE 2: fp16 gelu(acc+bias) -> outH[row][ldc]
// MODE 3: fp16 acc -> outH[row][ldc]
template<int MT, int NT, int MODE>
__global__ __launch_bounds__(256)
void hgemm(const __half* __restrict__ A, int lda,
           const __half* __restrict__ BT, int ldb,
           const float* __restrict__ bias,
           float* __restrict__ outF, __half* __restrict__ outH, int ldc) {
    const int tid = threadIdx.x, l = tid & 63, wid = tid >> 6;
    const int wm = wid >> 1, wn = wid & 1;
    const int row0 = blockIdx.y * (2 * MT * 16) + wm * (MT * 16);
    const int col0 = blockIdx.x * (2 * NT * 16) + wn * (NT * 16);
    const int z = blockIdx.z;
    const int rl = l & 15, kl = (l >> 4) * 8;
    const __half* Ap = A + (size_t)(row0 + rl) * lda + z * 128 + kl;
    const __half* Bp = BT + (size_t)(col0 + rl) * ldb + z * 128 + kl;

    f32x4 acc[MT][NT];
    #pragma unroll
    for (int mi = 0; mi < MT; mi++)
        #pragma unroll
        for (int ni = 0; ni < NT; ni++) acc[mi][ni] = (f32x4){0.f, 0.f, 0.f, 0.f};

    #pragma unroll
    for (int ks = 0; ks < 4; ks++) {
        f16x8 af[MT], bf[NT];
        #pragma unroll
        for (int mi = 0; mi < MT; mi++)
            af[mi] = *reinterpret_cast<const f16x8*>(Ap + (size_t)mi * 16 * lda + ks * 32);
        #pragma unroll
        for (int ni = 0; ni < NT; ni++)
            bf[ni] = *reinterpret_cast<const f16x8*>(Bp + (size_t)ni * 16 * ldb + ks * 32);
        #pragma unroll
        for (int mi = 0; mi < MT; mi++)
            #pragma unroll
            for (int ni = 0; ni < NT; ni++)
                acc[mi][ni] = __builtin_amdgcn_mfma_f32_16x16x32_f16(
                    af[mi], bf[ni], acc[mi][ni], 0, 0, 0);
    }

    const int orow = (l >> 4) * 4;
    #pragma unroll
    for (int mi = 0; mi < MT; mi++) {
        #pragma unroll
        for (int ni = 0; ni < NT; ni++) {
            int col = col0 + ni * 16 + rl;
            #pragma unroll
            for (int i = 0; i < 4; i++) {
                int row = row0 + mi * 16 + orow + i;
                float v = acc[mi][ni][i];
                if (MODE == 1) {
                    outF[((size_t)z * M + row) * 128 + col] = v;
                } else if (MODE == 2) {
                    outH[(size_t)row * ldc + col] = __float2half(gelu_f(v + bias[col]));
                } else {
                    outH[(size_t)row * ldc + col] = __float2half(v);
                }
            }
        }
    }
}

// ---------------- classifier: 128x128 tiles, XCD-bijective swizzle ------------
__global__ __launch_bounds__(256)
void hgemm_cls(const __half* __restrict__ A, const __half* __restrict__ BT,
               const float* __restrict__ bias, float* __restrict__ out) {
    constexpr int MT = 4, NT = 4;
    constexpr int MB = M / 128;               // 20
    constexpr int NB = VPAD / 128;            // 393
    constexpr int NWG = MB * NB;              // 7860
    constexpr int q = NWG / 8, r = NWG % 8;   // 982, 4
    int orig = blockIdx.x;
    int xcd = orig & 7, off = orig >> 3;
    int wg = (xcd < r ? xcd * (q + 1) : r * (q + 1) + (xcd - r) * q) + off;
    int mb = wg % MB, nb = wg / MB;           // m fastest -> same-nb blocks share XCD

    const int tid = threadIdx.x, l = tid & 63, wid = tid >> 6;
    const int wm = wid >> 1, wn = wid & 1;
    const int row0 = mb * 128 + wm * 64;
    const int col0 = nb * 128 + wn * 64;
    const int rl = l & 15, kl = (l >> 4) * 8;
    const __half* Ap = A + (size_t)(row0 + rl) * 128 + kl;
    const __half* Bp = BT + (size_t)(col0 + rl) * 128 + kl;

    f32x4 acc[MT][NT];
    #pragma unroll
    for (int mi = 0; mi < MT; mi++)
        #pragma unroll
        for (int ni = 0; ni < NT; ni++) acc[mi][ni] = (f32x4){0.f, 0.f, 0.f, 0.f};

    #pragma unroll
    for (int ks = 0; ks < 4; ks++) {
        f16x8 af[MT], bf[NT];
        #pragma unroll
        for (int mi = 0; mi < MT; mi++)
            af[mi] = *reinterpret_cast<const f16x8*>(Ap + (size_t)mi * 16 * 128 + ks * 32);
        #pragma unroll
        for (int ni = 0; ni < NT; ni++)
            bf[ni] = *reinterpret_cast<const f16x8*>(Bp + (size_t)ni * 16 * 128 + ks * 32);
        #pragma unroll
        for (int mi = 0; mi < MT; mi++)
            #pragma unroll
            for (int ni = 0; ni < NT; ni++)
                acc[mi][ni] = __builtin_amdgcn_mfma_f32_16x16x32_f16(
                    af[mi], bf[ni], acc[mi][ni], 0, 0, 0);
    }

    const int orow = (l >> 4) * 4;
    #pragma unroll
    for (int mi = 0; mi < MT; mi++) {
        #pragma unroll
        for (int ni = 0; ni < NT; ni++) {
            int col = col0 + ni * 16 + rl;
            if (col < V) {
                float bv = bias[col];
                #pragma unroll
                for (int i = 0; i < 4; i++) {
                    int row = row0 + mi * 16 + orow + i;
                    out[(size_t)row * V + col] = acc[mi][ni][i] + bv;
                }
            }
        }
    }
}

// ---------------- fused attention: scores+softmax+PV per (b,h) ----------------
__device__ __forceinline__ void load_h8(const __half* p, float* dst) {
    float4 raw = *reinterpret_cast<const float4*>(p);
    const __half2* h2 = reinterpret_cast<const __half2*>(&raw);
    float2 f;
    f = __half22float2(h2[0]); dst[0] = f.x; dst[1] = f.y;
    f = __half22float2(h2[1]); dst[2] = f.x; dst[3] = f.y;
    f = __half22float2(h2[2]); dst[4] = f.x; dst[5] = f.y;
    f = __half22float2(h2[3]); dst[6] = f.x; dst[7] = f.y;
}

__global__ __launch_bounds__(256)
void attn_fused(const __half* __restrict__ qkv, __half* __restrict__ o) {
    __shared__ float qS[T][DH];      // 20 KB, reused for V in PV phase
    __shared__ float pS[T][T];       // 25.6 KB
    int bh = blockIdx.x;
    int b = bh >> 3, h = bh & 7;
    const __half* base  = qkv + (size_t)b * T * QKVN + h * DH;
    const __half* kbase = base + HD;
    const __half* vbase = base + 2 * HD;

    for (int i = threadIdx.x; i < T * 8; i += 256) {   // q: T*64 halves
        int t = i >> 3, c8 = i & 7;
        load_h8(base + (size_t)t * QKVN + c8 * 8, &qS[t][c8 * 8]);
    }
    __syncthreads();

    for (int i = threadIdx.x; i < T * T; i += 256) {
        int t = i / T, s = i - t * T;
        float val = -INFINITY;
        if (s <= t) {
            const __half* krow = kbase + (size_t)s * QKVN;
            float accv = 0.0f;
            #pragma unroll
            for (int e8 = 0; e8 < 8; e8++) {
                float kf[8]; load_h8(krow + e8 * 8, kf);
                const float* qf = &qS[t][e8 * 8];
                #pragma unroll
                for (int u = 0; u < 8; u++) accv = fmaf(kf[u], qf[u], accv);
            }
            val = accv * 0.125f;
        }
        pS[t][s] = val;
    }
    __syncthreads();                 // scores done; qS free, pS raw

    // load v into qS (overwrites q) — concurrent with softmax below
    for (int i = threadIdx.x; i < T * 8; i += 256) {
        int t = i >> 3, c8 = i & 7;
        load_h8(vbase + (size_t)t * QKVN + c8 * 8, &qS[t][c8 * 8]);
    }

    int wid = threadIdx.x >> 6, lane = threadIdx.x & 63;
    for (int t = wid; t < T; t += 4) {
        float v0 = pS[t][lane];
        float v1 = (lane < T - 64) ? pS[t][64 + lane] : -INFINITY;
        float mx = fmaxf(v0, v1);
        #pragma unroll
        for (int off = 32; off; off >>= 1) mx = fmaxf(mx, __shfl_xor(mx, off));
        float e0 = expf(v0 - mx);
        float e1 = (lane < T - 64) ? expf(v1 - mx) : 0.0f;
        float ss = e0 + e1;
        #pragma unroll
        for (int off = 32; off; off >>= 1) ss += __shfl_xor(ss, off);
        float rs = 1.0f / ss;
        pS[t][lane] = e0 * rs;
        if (lane < T - 64) pS[t][64 + lane] = e1 * rs;
    }
    __syncthreads();

    for (int i = threadIdx.x; i < T * DH; i += 256) {
        int t = i >> 6, e = i & 63;
        float accv = 0.0f;
        for (int s = 0; s <= t; s++) accv = fmaf(pS[t][s], qS[s][e], accv);
        o[((size_t)b * T + t) * HD + h * DH + e] = __float2half(accv);
    }
}

// ---------------- launch ----------------
extern "C" void kernel_launch(void* const* d_in, const int* in_sizes, int n_in,
                              void* d_out, int out_size, void* d_ws, size_t ws_size,
                              hipStream_t stream) {
    const int*   x     = (const int*)d_in[0];
    const float* tok   = (const float*)d_in[1];
    const float* pos   = (const float*)d_in[2];
    const float* Wq    = (const float*)d_in[3];
    const float* Wk    = (const float*)d_in[4];
    const float* Wv    = (const float*)d_in[5];
    const float* Wo    = (const float*)d_in[6];
    const float* bo    = (const float*)d_in[7];
    const float* ln1g  = (const float*)d_in[8];
    const float* ln1b  = (const float*)d_in[9];
    const float* ln2g  = (const float*)d_in[10];
    const float* ln2b  = (const float*)d_in[11];
    const float* W1    = (const float*)d_in[12];
    const float* b1    = (const float*)d_in[13];
    const float* W2    = (const float*)d_in[14];
    const float* b2    = (const float*)d_in[15];
    const float* lnfg  = (const float*)d_in[16];
    const float* lnfb  = (const float*)d_in[17];
    const float* Wcls  = (const float*)d_in[18];
    const float* bcls  = (const float*)d_in[19];
    float* out = (float*)d_out;

    char* w = (char*)d_ws;
    float*  h     = (float*)w;                 w += (size_t)M * D * 4;      // fp32 residual
    __half* a_h   = (__half*)w;                w += (size_t)M * D * 2;
    __half* qkvh  = (__half*)w;                w += (size_t)M * QKVN * 2;
    __half* o_h   = (__half*)w;                w += (size_t)M * HD * 2;
    __half* mlp   = (__half*)w;                w += (size_t)M * DMLP * 2;
    float*  pbuf  = (float*)w;                 w += (size_t)4 * M * D * 4;
    __half* WqkvT = (__half*)w;                w += (size_t)L * QKVN * D * 2;
    __half* WoT   = (__half*)w;                w += (size_t)L * D * HD * 2;
    __half* W1T   = (__half*)w;                w += (size_t)L * DMLP * D * 2;
    __half* W2T   = (__half*)w;                w += (size_t)L * D * DMLP * 2;
    __half* WclsT = (__half*)w;                w += (size_t)VPAD * D * 2;

    // weight prep (every call; ws is re-poisoned between calls)
    prep_small<<<(L * QKVN * D + 3 * L * DMLP * D) / 256, 256, 0, stream>>>(
        Wq, Wk, Wv, Wo, W1, W2, WqkvT, WoT, W1T, W2T);
    prep_wcls<<<VPAD / 32, 256, 0, stream>>>(Wcls, WclsT);
    // embedding + first LN fused
    embed_ln<<<M / 4, 256, 0, stream>>>(x, tok, pos, ln1g, ln1b, h, a_h);

    for (int l = 0; l < L; l++) {
        // qkv = a @ Wqkv : [2560,128]@[128,1536] fp16
        hgemm<2, 2, 3><<<dim3(QKVN / 64, M / 64, 1), 256, 0, stream>>>(
            a_h, D, WqkvT + (size_t)l * QKVN * D, D, nullptr, nullptr, qkvh, QKVN);
        attn_fused<<<B * H, 256, 0, stream>>>(qkvh, o_h);
        // h += o @ Wo + bo (split-K=4), then LN2 -> a_h
        hgemm<2, 2, 1><<<dim3(D / 64, M / 64, 4), 256, 0, stream>>>(
            o_h, HD, WoT + (size_t)l * D * HD, HD, nullptr, pbuf, nullptr, D);
        combine_ln<<<M / 4, 256, 0, stream>>>(
            pbuf, bo + l * D, ln2g + l * D, ln2b + l * D, h, a_h);

        // mlp = gelu(a @ W1 + b1) : [2560,128]@[128,512]
        hgemm<2, 2, 2><<<dim3(DMLP / 64, M / 64, 1), 256, 0, stream>>>(
            a_h, D, W1T + (size_t)l * DMLP * D, D, b1 + l * DMLP, nullptr, mlp, DMLP);
        // h += mlp @ W2 + b2 (split-K=4), then LN1[l+1] (or final LN) -> a_h
        hgemm<2, 2, 1><<<dim3(D / 64, M / 64, 4), 256, 0, stream>>>(
            mlp, DMLP, W2T + (size_t)l * D * DMLP, DMLP, nullptr, pbuf, nullptr, D);
        const float* ng = (l + 1 < L) ? ln1g + (l + 1) * D : lnfg;
        const float* nb = (l + 1 < L) ? ln1b + (l + 1) * D : lnfb;
        combine_ln<<<M / 4, 256, 0, stream>>>(pbuf, b2 + l * D, ng, nb, h, a_h);
    }

    // logits = a @ Wcls + bcls : [2560,128]@[128,50257]
    hgemm_cls<<<(M / 128) * (VPAD / 128), 256, 0, stream>>>(a_h, WclsT, bcls, out);
}

// Round 6
// 1225.350 us; speedup vs baseline: 2.0826x; 1.1642x over previous
//
#include <hip/hip_runtime.h>
#include <hip/hip_bf16.h>
#include <hip/hip_fp16.h>
#include <math.h>

// ---------------- problem dims (compile-time) ----------------
constexpr int B = 32, T = 80, D = 128, H = 8, DH = 64, DMLP = 512, L = 8, V = 50257;
constexpr int M = B * T;            // 2560 token rows
constexpr int HD = H * DH;          // 512
constexpr int QKVN = 3 * HD;        // 1536
constexpr int VPAD = 50304;         // 393*128, padded classifier cols

typedef _Float16 f16x8 __attribute__((ext_vector_type(8)));
typedef float f32x4 __attribute__((ext_vector_type(4)));

__device__ __forceinline__ float gelu_f(float x) {
    return 0.5f * x * (1.0f + erff(x * 0.70710678118654752f));
}

// ---- embedding + first LN: h = tok_emb[x]+pos_emb; a = LN(h,g,b) fp16 -------
__global__ __launch_bounds__(256)
void embed_ln(const int* __restrict__ x, const float* __restrict__ tok,
              const float* __restrict__ pos, const float* __restrict__ g,
              const float* __restrict__ bb, float* __restrict__ h,
              __half* __restrict__ out) {
    int wid = threadIdx.x >> 6, lane = threadIdx.x & 63;
    int row = blockIdx.x * 4 + wid;
    int t = row % T;
    const float* te = tok + (size_t)x[row] * D;
    const float* pe = pos + (size_t)t * D;
    float v0 = te[lane]      + pe[lane];
    float v1 = te[64 + lane] + pe[64 + lane];
    int i0 = row * D + lane, i1 = i0 + 64;
    h[i0] = v0; h[i1] = v1;
    float s = v0 + v1;
    #pragma unroll
    for (int off = 32; off; off >>= 1) s += __shfl_xor(s, off);
    float mean = s * (1.0f / 128.0f);
    float d0 = v0 - mean, d1 = v1 - mean;
    float q = d0 * d0 + d1 * d1;
    #pragma unroll
    for (int off = 32; off; off >>= 1) q += __shfl_xor(q, off);
    float inv = rsqrtf(q * (1.0f / 128.0f) + 1e-5f);
    out[i0] = __float2half(d0 * inv * g[lane]      + bb[lane]);
    out[i1] = __float2half(d1 * inv * g[64 + lane] + bb[64 + lane]);
}

// ---- fused: h += (sum of 8 split-K planes + bias); then LN(h) -> fp16 out ----
__global__ __launch_bounds__(256)
void combine_ln(const float* __restrict__ p, const float* __restrict__ bias,
                const float* __restrict__ g, const float* __restrict__ bb,
                float* __restrict__ h, __half* __restrict__ out) {
    constexpr int plane = M * D;
    int wid = threadIdx.x >> 6, lane = threadIdx.x & 63;
    int row = blockIdx.x * 4 + wid;
    int i0 = row * D + lane, i1 = i0 + 64;
    float v0 = h[i0] + bias[lane];
    float v1 = h[i1] + bias[64 + lane];
    #pragma unroll
    for (int k = 0; k < 8; k++) { v0 += p[i0 + k * plane]; v1 += p[i1 + k * plane]; }
    h[i0] = v0; h[i1] = v1;
    float s = v0 + v1;
    #pragma unroll
    for (int off = 32; off; off >>= 1) s += __shfl_xor(s, off);
    float mean = s * (1.0f / 128.0f);
    float d0 = v0 - mean, d1 = v1 - mean;
    float q = d0 * d0 + d1 * d1;
    #pragma unroll
    for (int off = 32; off; off >>= 1) q += __shfl_xor(q, off);
    float inv = rsqrtf(q * (1.0f / 128.0f) + 1e-5f);
    out[i0] = __float2half(d0 * inv * g[lane]      + bb[lane]);
    out[i1] = __float2half(d1 * inv * g[64 + lane] + bb[64 + lane]);
}

// ---------------- weight prep: fp32 -> fp16 transposed [N][K] ----------------
__global__ __launch_bounds__(256)
void prep_small(const float* __restrict__ Wq, const float* __restrict__ Wk,
                const float* __restrict__ Wv, const float* __restrict__ Wo,
                const float* __restrict__ W1, const float* __restrict__ W2,
                __half* __restrict__ WqkvT, __half* __restrict__ WoT,
                __half* __restrict__ W1T, __half* __restrict__ W2T) {
    int id = blockIdx.x * 256 + threadIdx.x;
    if (id < L * QKVN * D) {                 // 1572864
        int d = id & 127; int lc = id >> 7; int c = lc % QKVN; int l = lc / QKVN;
        int e = c & 63, hh = (c >> 6) & 7, wsel = c >> 9;
        const float* src = (wsel == 0) ? Wq : (wsel == 1) ? Wk : Wv;
        WqkvT[id] = __float2half(src[(((size_t)l * H + hh) * D + d) * DH + e]);
    } else {
        int id2 = id - L * QKVN * D;
        int which = id2 >> 19;               // /524288
        int r = id2 & 524287;
        if (which == 0) {                    // WoT[n][k] = Wo[l][k][n]
            int k = r & 511, n = (r >> 9) & 127, l = r >> 16;
            WoT[r] = __float2half(Wo[((size_t)l * 512 + k) * 128 + n]);
        } else if (which == 1) {             // W1T[n][k] = W1[l][k][n]
            int k = r & 127, n = (r >> 7) & 511, l = r >> 16;
            W1T[r] = __float2half(W1[((size_t)l * 128 + k) * 512 + n]);
        } else {                             // W2T like WoT
            int k = r & 511, n = (r >> 9) & 127, l = r >> 16;
            W2T[r] = __float2half(W2[((size_t)l * 512 + k) * 128 + n]);
        }
    }
}

// ---- Wcls [128][50257] -> WclsT [50304][128] fp16 (LDS transpose, 16.9 KB) ----
__global__ __launch_bounds__(256)
void prep_wcls(const float* __restrict__ Wcls, __half* __restrict__ WT) {
    __shared__ float tile[128][33];          // 32 n-cols per block, +1 pad
    int n0 = blockIdx.x * 32;
    for (int i = threadIdx.x; i < 128 * 32; i += 256) {
        int k = i >> 5, j = i & 31;
        int n = n0 + j;
        tile[k][j] = (n < V) ? Wcls[(size_t)k * V + n] : 0.0f;
    }
    __syncthreads();
    for (int i = threadIdx.x; i < 32 * 64; i += 256) {
        int j = i >> 6, kp = i & 63;         // kp = half2 index along k
        __half2 hv = __floats2half2_rn(tile[2 * kp][j], tile[2 * kp + 1][j]);
        *reinterpret_cast<__half2*>(WT + (size_t)(n0 + j) * 128 + 2 * kp) = hv;
    }
}

// ------- generic fp16 MFMA GEMM, K-chunk = KS*32 per z-plane ------------------
// A [M][lda] fp16 row-major, BT [N][ldb] fp16 (k-contiguous).
// MODE 1: fp32 partial plane z -> outF[z][M][128]
// MODE 2: fp16 gelu(acc+bias) -> outH[row][ldc]
template<int MT, int NT, int KS, int MODE>
__global__ __launch_bounds__(256)
void hgemm(const __half* __restrict__ A, int lda,
           const __half* __restrict__ BT, int ldb,
           const float* __restrict__ bias,
           float* __restrict__ outF, __half* __restrict__ outH, int ldc) {
    const int tid = threadIdx.x, l = tid & 63, wid = tid >> 6;
    const int wm = wid >> 1, wn = wid & 1;
    const int row0 = blockIdx.y * (2 * MT * 16) + wm * (MT * 16);
    const int col0 = blockIdx.x * (2 * NT * 16) + wn * (NT * 16);
    const int z = blockIdx.z;
    const int rl = l & 15, kl = (l >> 4) * 8;
    const __half* Ap = A + (size_t)(row0 + rl) * lda + z * (KS * 32) + kl;
    const __half* Bp = BT + (size_t)(col0 + rl) * ldb + z * (KS * 32) + kl;

    f32x4 acc[MT][NT];
    #pragma unroll
    for (int mi = 0; mi < MT; mi++)
        #pragma unroll
        for (int ni = 0; ni < NT; ni++) acc[mi][ni] = (f32x4){0.f, 0.f, 0.f, 0.f};

    #pragma unroll
    for (int ks = 0; ks < KS; ks++) {
        f16x8 af[MT], bf[NT];
        #pragma unroll
        for (int mi = 0; mi < MT; mi++)
            af[mi] = *reinterpret_cast<const f16x8*>(Ap + (size_t)mi * 16 * lda + ks * 32);
        #pragma unroll
        for (int ni = 0; ni < NT; ni++)
            bf[ni] = *reinterpret_cast<const f16x8*>(Bp + (size_t)ni * 16 * ldb + ks * 32);
        #pragma unroll
        for (int mi = 0; mi < MT; mi++)
            #pragma unroll
            for (int ni = 0; ni < NT; ni++)
                acc[mi][ni] = __builtin_amdgcn_mfma_f32_16x16x32_f16(
                    af[mi], bf[ni], acc[mi][ni], 0, 0, 0);
    }

    const int orow = (l >> 4) * 4;
    #pragma unroll
    for (int mi = 0; mi < MT; mi++) {
        #pragma unroll
        for (int ni = 0; ni < NT; ni++) {
            int col = col0 + ni * 16 + rl;
            #pragma unroll
            for (int i = 0; i < 4; i++) {
                int row = row0 + mi * 16 + orow + i;
                float v = acc[mi][ni][i];
                if (MODE == 1) {
                    outF[((size_t)z * M + row) * 128 + col] = v;
                } else {
                    outH[(size_t)row * ldc + col] = __float2half(gelu_f(v + bias[col]));
                }
            }
        }
    }
}

// ---------------- classifier: 128x128 tiles, XCD-bijective swizzle ------------
__global__ __launch_bounds__(256)
void hgemm_cls(const __half* __restrict__ A, const __half* __restrict__ BT,
               const float* __restrict__ bias, float* __restrict__ out) {
    constexpr int MT = 4, NT = 4;
    constexpr int MB = M / 128;               // 20
    constexpr int NB = VPAD / 128;            // 393
    constexpr int NWG = MB * NB;              // 7860
    constexpr int q = NWG / 8, r = NWG % 8;   // 982, 4
    int orig = blockIdx.x;
    int xcd = orig & 7, off = orig >> 3;
    int wg = (xcd < r ? xcd * (q + 1) : r * (q + 1) + (xcd - r) * q) + off;
    int mb = wg % MB, nb = wg / MB;           // m fastest -> same-nb blocks share XCD

    const int tid = threadIdx.x, l = tid & 63, wid = tid >> 6;
    const int wm = wid >> 1, wn = wid & 1;
    const int row0 = mb * 128 + wm * 64;
    const int col0 = nb * 128 + wn * 64;
    const int rl = l & 15, kl = (l >> 4) * 8;
    const __half* Ap = A + (size_t)(row0 + rl) * 128 + kl;
    const __half* Bp = BT + (size_t)(col0 + rl) * 128 + kl;

    f32x4 acc[MT][NT];
    #pragma unroll
    for (int mi = 0; mi < MT; mi++)
        #pragma unroll
        for (int ni = 0; ni < NT; ni++) acc[mi][ni] = (f32x4){0.f, 0.f, 0.f, 0.f};

    #pragma unroll
    for (int ks = 0; ks < 4; ks++) {
        f16x8 af[MT], bf[NT];
        #pragma unroll
        for (int mi = 0; mi < MT; mi++)
            af[mi] = *reinterpret_cast<const f16x8*>(Ap + (size_t)mi * 16 * 128 + ks * 32);
        #pragma unroll
        for (int ni = 0; ni < NT; ni++)
            bf[ni] = *reinterpret_cast<const f16x8*>(Bp + (size_t)ni * 16 * 128 + ks * 32);
        #pragma unroll
        for (int mi = 0; mi < MT; mi++)
            #pragma unroll
            for (int ni = 0; ni < NT; ni++)
                acc[mi][ni] = __builtin_amdgcn_mfma_f32_16x16x32_f16(
                    af[mi], bf[ni], acc[mi][ni], 0, 0, 0);
    }

    const int orow = (l >> 4) * 4;
    #pragma unroll
    for (int mi = 0; mi < MT; mi++) {
        #pragma unroll
        for (int ni = 0; ni < NT; ni++) {
            int col = col0 + ni * 16 + rl;
            if (col < V) {
                float bv = bias[col];
                #pragma unroll
                for (int i = 0; i < 4; i++) {
                    int row = row0 + mi * 16 + orow + i;
                    out[(size_t)row * V + col] = acc[mi][ni][i] + bv;
                }
            }
        }
    }
}

// ---- fused per-(b,h): q/k/v projection + scores + softmax + PV (all MFMA) ----
// LDS overlay (bytes):
//   [0,11520)      qS [80][72]h   (ph2-3)  | pH [80][96]h (ph4-5) spans [0,15360)
//   [11520,23040)  kS [80][72]h   (ph2-3)
//   [23040,35328)  vT [64][96]h   (ph2-5)
//   [35328,57088)  aS [80][136]h  (ph1-2)  | pS [80][84]f (ph3-4) spans [35328,62208)
__global__ __launch_bounds__(256)
void attn_layer(const __half* __restrict__ a, const __half* __restrict__ Wl,
                __half* __restrict__ o) {
    __shared__ __align__(16) char smem[62208];
    __half* qS = (__half*)smem;                 // stride 72
    __half* kS = (__half*)(smem + 11520);       // stride 72
    __half* vT = (__half*)(smem + 23040);       // stride 96
    __half* aS = (__half*)(smem + 35328);       // stride 136
    float*  pS = (float*)(smem + 35328);        // stride 84
    __half* pH = (__half*)smem;                 // stride 96

    const int bh = blockIdx.x, b = bh >> 3, hh = bh & 7;
    const int tid = threadIdx.x, l = tid & 63, wid = tid >> 6;
    const int rl = l & 15, kq = (l >> 4) * 8, orow = (l >> 4) * 4;

    // phase 1: stage a rows, zero vT pad cols
    const __half* arow = a + (size_t)b * T * D;
    for (int i = tid; i < T * 16; i += 256) {
        int t = i >> 4, c = i & 15;
        *reinterpret_cast<float4*>(aS + t * 136 + c * 8) =
            *reinterpret_cast<const float4*>(arow + t * 128 + c * 8);
    }
    for (int i = tid; i < 64 * 16; i += 256) {
        int e = i >> 4, j = i & 15;
        vT[e * 96 + 80 + j] = __float2half(0.f);
    }
    __syncthreads();

    // phase 2: q,k,v = a @ W slices (K=128)
    for (int tile = wid; tile < 60; tile += 4) {
        int which = tile / 20, sub = tile % 20, mt = sub >> 2, nt = sub & 3;
        int col = which * 512 + hh * 64 + nt * 16 + rl;
        const __half* Bp  = Wl + (size_t)col * 128 + kq;
        const __half* Apl = aS + (mt * 16 + rl) * 136 + kq;
        f32x4 acc = (f32x4){0.f, 0.f, 0.f, 0.f};
        #pragma unroll
        for (int ks = 0; ks < 4; ks++)
            acc = __builtin_amdgcn_mfma_f32_16x16x32_f16(
                *reinterpret_cast<const f16x8*>(Apl + ks * 32),
                *reinterpret_cast<const f16x8*>(Bp + ks * 32), acc, 0, 0, 0);
        if (which == 2) {
            #pragma unroll
            for (int i = 0; i < 4; i++)
                vT[(nt * 16 + rl) * 96 + mt * 16 + orow + i] = __float2half(acc[i]);
        } else {
            __half* dst = (which == 0) ? qS : kS;
            #pragma unroll
            for (int i = 0; i < 4; i++)
                dst[(mt * 16 + orow + i) * 72 + nt * 16 + rl] = __float2half(acc[i]);
        }
    }
    __syncthreads();

    // phase 3: scores = (q @ k^T) * 1/8, causal mask (K=64)
    for (int tile = wid; tile < 25; tile += 4) {
        int mt = tile / 5, st = tile % 5;
        const __half* Aq = qS + (mt * 16 + rl) * 72 + kq;
        const __half* Bk = kS + (st * 16 + rl) * 72 + kq;
        f32x4 acc = (f32x4){0.f, 0.f, 0.f, 0.f};
        #pragma unroll
        for (int ks = 0; ks < 2; ks++)
            acc = __builtin_amdgcn_mfma_f32_16x16x32_f16(
                *reinterpret_cast<const f16x8*>(Aq + ks * 32),
                *reinterpret_cast<const f16x8*>(Bk + ks * 32), acc, 0, 0, 0);
        #pragma unroll
        for (int i = 0; i < 4; i++) {
            int t = mt * 16 + orow + i, s = st * 16 + rl;
            pS[t * 84 + s] = (s <= t) ? acc[i] * 0.125f : -INFINITY;
        }
    }
    __syncthreads();

    // phase 4: row softmax -> pH fp16 (cols 80..95 zeroed)
    for (int t = wid; t < T; t += 4) {
        float v0 = pS[t * 84 + l];
        float v1 = (l < 16) ? pS[t * 84 + 64 + l] : -INFINITY;
        float mx = fmaxf(v0, v1);
        #pragma unroll
        for (int off = 32; off; off >>= 1) mx = fmaxf(mx, __shfl_xor(mx, off));
        float e0 = expf(v0 - mx);
        float e1 = (l < 16) ? expf(v1 - mx) : 0.0f;
        float ss = e0 + e1;
        #pragma unroll
        for (int off = 32; off; off >>= 1) ss += __shfl_xor(ss, off);
        float rs = 1.0f / ss;
        pH[t * 96 + l] = __float2half(e0 * rs);
        if (l < 32) pH[t * 96 + 64 + l] = __float2half((l < 16) ? e1 * rs : 0.0f);
    }
    __syncthreads();

    // phase 5: o = p @ v (K=96, zero-padded)
    for (int tile = wid; tile < 20; tile += 4) {
        int mt = tile >> 2, et = tile & 3;
        const __half* Apv = pH + (mt * 16 + rl) * 96 + kq;
        const __half* Bv  = vT + (et * 16 + rl) * 96 + kq;
        f32x4 acc = (f32x4){0.f, 0.f, 0.f, 0.f};
        #pragma unroll
        for (int ks = 0; ks < 3; ks++)
            acc = __builtin_amdgcn_mfma_f32_16x16x32_f16(
                *reinterpret_cast<const f16x8*>(Apv + ks * 32),
                *reinterpret_cast<const f16x8*>(Bv + ks * 32), acc, 0, 0, 0);
        #pragma unroll
        for (int i = 0; i < 4; i++)
            o[((size_t)b * T + mt * 16 + orow + i) * HD + hh * 64 + et * 16 + rl]
                = __float2half(acc[i]);
    }
}

// ---------------- launch ----------------
extern "C" void kernel_launch(void* const* d_in, const int* in_sizes, int n_in,
                              void* d_out, int out_size, void* d_ws, size_t ws_size,
                              hipStream_t stream) {
    const int*   x     = (const int*)d_in[0];
    const float* tok   = (const float*)d_in[1];
    const float* pos   = (const float*)d_in[2];
    const float* Wq    = (const float*)d_in[3];
    const float* Wk    = (const float*)d_in[4];
    const float* Wv    = (const float*)d_in[5];
    const float* Wo    = (const float*)d_in[6];
    const float* bo    = (const float*)d_in[7];
    const float* ln1g  = (const float*)d_in[8];
    const float* ln1b  = (const float*)d_in[9];
    const float* ln2g  = (const float*)d_in[10];
    const float* ln2b  = (const float*)d_in[11];
    const float* W1    = (const float*)d_in[12];
    const float* b1    = (const float*)d_in[13];
    const float* W2    = (const float*)d_in[14];
    const float* b2    = (const float*)d_in[15];
    const float* lnfg  = (const float*)d_in[16];
    const float* lnfb  = (const float*)d_in[17];
    const float* Wcls  = (const float*)d_in[18];
    const float* bcls  = (const float*)d_in[19];
    float* out = (float*)d_out;

    char* w = (char*)d_ws;
    float*  h     = (float*)w;                 w += (size_t)M * D * 4;      // fp32 residual
    __half* a_h   = (__half*)w;                w += (size_t)M * D * 2;
    __half* o_h   = (__half*)w;                w += (size_t)M * HD * 2;
    __half* mlp   = (__half*)w;                w += (size_t)M * DMLP * 2;
    float*  pbuf  = (float*)w;                 w += (size_t)8 * M * D * 4;
    __half* WqkvT = (__half*)w;                w += (size_t)L * QKVN * D * 2;
    __half* WoT   = (__half*)w;                w += (size_t)L * D * HD * 2;
    __half* W1T   = (__half*)w;                w += (size_t)L * DMLP * D * 2;
    __half* W2T   = (__half*)w;                w += (size_t)L * D * DMLP * 2;
    __half* WclsT = (__half*)w;                w += (size_t)VPAD * D * 2;

    // weight prep (every call; ws is re-poisoned between calls)
    prep_small<<<(L * QKVN * D + 3 * L * DMLP * D) / 256, 256, 0, stream>>>(
        Wq, Wk, Wv, Wo, W1, W2, WqkvT, WoT, W1T, W2T);
    prep_wcls<<<VPAD / 32, 256, 0, stream>>>(Wcls, WclsT);
    // embedding + first LN fused
    embed_ln<<<M / 4, 256, 0, stream>>>(x, tok, pos, ln1g, ln1b, h, a_h);

    for (int l = 0; l < L; l++) {
        // fused qkv-projection + attention per (b,h)
        attn_layer<<<B * H, 256, 0, stream>>>(
            a_h, WqkvT + (size_t)l * QKVN * D, o_h);
        // h += o @ Wo + bo (split-K=8), then LN2 -> a_h
        hgemm<2, 2, 2, 1><<<dim3(D / 64, M / 64, 8), 256, 0, stream>>>(
            o_h, HD, WoT + (size_t)l * D * HD, HD, nullptr, pbuf, nullptr, D);
        combine_ln<<<M / 4, 256, 0, stream>>>(
            pbuf, bo + l * D, ln2g + l * D, ln2b + l * D, h, a_h);

        // mlp = gelu(a @ W1 + b1) : [2560,128]@[128,512]
        hgemm<2, 2, 4, 2><<<dim3(DMLP / 64, M / 64, 1), 256, 0, stream>>>(
            a_h, D, W1T + (size_t)l * DMLP * D, D, b1 + l * DMLP, nullptr, mlp, DMLP);
        // h += mlp @ W2 + b2 (split-K=8), then LN1[l+1] (or final LN) -> a_h
        hgemm<2, 2, 2, 1><<<dim3(D / 64, M / 64, 8), 256, 0, stream>>>(
            mlp, DMLP, W2T + (size_t)l * D * DMLP, DMLP, nullptr, pbuf, nullptr, D);
        const float* ng = (l + 1 < L) ? ln1g + (l + 1) * D : lnfg;
        const float* nb = (l + 1 < L) ? ln1b + (l + 1) * D : lnfb;
        combine_ln<<<M / 4, 256, 0, stream>>>(pbuf, b2 + l * D, ng, nb, h, a_h);
    }

    // logits = a @ Wcls + bcls : [2560,128]@[128,50257]
    hgemm_cls<<<(M / 128) * (VPAD / 128), 256, 0, stream>>>(a_h, WclsT, bcls, out);
}